// Round 6
// baseline (16609.485 us; speedup 1.0000x reference)
//
#include <hip/hip_runtime.h>

#define B_ 128
#define S_ 4096
#define IN_ 6
#define N_ 64
#define MOT_ 3
#define UNF 6
#define EPS_ 1e-8f
#define LOG2E 1.4426950408889634f

// ---- VALU-pipe cross-lane pair-sums over lane bits 4 and 5 ----
__device__ __forceinline__ float red16(float x) {
#if __has_builtin(__builtin_amdgcn_permlane16_swap)
    auto r = __builtin_amdgcn_permlane16_swap(__float_as_int(x), __float_as_int(x),
                                              false, false);
    return __int_as_float((int)r[0]) + __int_as_float((int)r[1]);
#else
    return x + __shfl_xor(x, 16, 64);
#endif
}
__device__ __forceinline__ float red32(float x) {
#if __has_builtin(__builtin_amdgcn_permlane32_swap)
    auto r = __builtin_amdgcn_permlane32_swap(__float_as_int(x), __float_as_int(x),
                                              false, false);
    return __int_as_float((int)r[0]) + __int_as_float((int)r[1]);
#else
    return x + __shfl_xor(x, 32, 64);
#endif
}

// barrier with LDS-only drain (no vmcnt: global loads/stores stay in flight)
__device__ __forceinline__ void lds_barrier() {
    asm volatile("s_waitcnt lgkmcnt(0)" ::: "memory");
    __builtin_amdgcn_s_barrier();
}

// TWO chains per block, interleaved in-lane for ILP: the trans-pipe bursts of
// one chain overlap the LDS-roundtrip/barrier latency of the other, and the
// exchange cost (1 barrier) is amortized over both chains. 256 threads =
// 4 waves = 1 wave/SIMD. Wave w owns output columns w*16..w*16+15; lane
// l = (cc=l>>4 j-chunk of 16, ii=l&15 col). Synapse params are SHARED
// between the two chains (same W/Mu/Sig/Erev).
__launch_bounds__(256, 1)
__global__ void ltc_kernel(
    const float* __restrict__ x,
    const float* __restrict__ mean_us, const float* __restrict__ std_us,
    const float* __restrict__ input_w, const float* __restrict__ input_b,
    const float* __restrict__ output_w, const float* __restrict__ output_b,
    const float* __restrict__ gleak, const float* __restrict__ vleak,
    const float* __restrict__ cm,
    const float* __restrict__ sW, const float* __restrict__ sMu,
    const float* __restrict__ sSig, const float* __restrict__ sErev,
    const float* __restrict__ W, const float* __restrict__ Mu,
    const float* __restrict__ Sig, const float* __restrict__ Erev,
    float* __restrict__ out)
{
    const int t    = threadIdx.x;
    const int lane = t & 63;
    const int w    = t >> 6;      // wave 0..3
    const int cc   = lane >> 4;   // j-chunk 0..3 (16 j's each)
    const int ii   = lane & 15;   // column within wave's block
    const int myCol = w * 16 + ii;
    const int jb   = cc * 16;

    __shared__ __align__(16) float vbuf[2][2][N_];      // [parity][chain][col]
    __shared__ float s_lds[2][IN_][N_][2];              // [chain][in][col][{n,d}]

    // --- recurrent synapse params: 16 synapses (j=jb..jb+15) of column myCol ---
    // sigmoid((v-mu)*sig) = 1/(1+exp2(v*A + Bc)), A=-sig*log2e, Bc=mu*sig*log2e
    float A[16], Bc[16], Wr[16], We[16];
#pragma unroll
    for (int jj = 0; jj < 16; ++jj) {
        int idx = (jb + jj) * N_ + myCol;
        float sg = Sig[idx], m = Mu[idx], ww = W[idx], e = Erev[idx];
        A[jj]  = -sg * LOG2E;
        Bc[jj] = m * sg * LOG2E;
        Wr[jj] = ww;
        We[jj] = ww * e;
    }

    // --- per-column state consts (shared by both chains) ---
    const float cmt = cm[myCol] * (float)UNF;
    const float glk = gleak[myCol];
    const float gv  = glk * vleak[myCol];
    const float dbase = cmt + glk + EPS_;

    // --- sensory params: wave w handles input w; waves 0,1 also input w+4 ---
    const int i0 = w;             // always valid (w<4 < IN_=6)
    const int i1 = w + 4;         // valid for w<2
    const bool has1 = (w < 2);
    float SA0, SB0, SWv0, SWe0, ns0, nb0;
    {
        int idx = i0 * N_ + lane;
        float sg = sSig[idx], m = sMu[idx], ww = sW[idx], e = sErev[idx];
        SA0 = -sg * LOG2E; SB0 = m * sg * LOG2E; SWv0 = ww; SWe0 = ww * e;
        ns0 = input_w[i0] / std_us[i0];
        nb0 = input_b[i0] - mean_us[i0] / std_us[i0] * input_w[i0];
    }
    float SA1 = 0.f, SB1 = 0.f, SWv1 = 0.f, SWe1 = 0.f, ns1 = 0.f, nb1 = 0.f;
    if (has1) {
        int idx = i1 * N_ + lane;
        float sg = sSig[idx], m = sMu[idx], ww = sW[idx], e = sErev[idx];
        SA1 = -sg * LOG2E; SB1 = m * sg * LOG2E; SWv1 = ww; SWe1 = ww * e;
        ns1 = input_w[i1] / std_us[i1];
        nb1 = input_b[i1] - mean_us[i1] / std_us[i1] * input_w[i1];
    }

    // --- output consts (lanes 0..2 of wave 0 hold motor columns 0..2) ---
    float OW = 0.f, OB = 0.f;
    if (t < MOT_) {
        OW = output_w[t] * std_us[t];
        OB = output_b[t] * std_us[t] + mean_us[t];
    }

    const int bA = blockIdx.x * 2;
    const int bB = bA + 1;
    const float* xA = x + (size_t)bA * S_ * IN_;
    const float* xB = x + (size_t)bB * S_ * IN_;
    float* oA = out + (size_t)bA * S_ * MOT_;
    float* oB = out + (size_t)bB * S_ * MOT_;

    // --- init: v=0, sensory activations for step 0, both chains ---
    if (t < N_) { vbuf[0][0][t] = 0.f; vbuf[0][1][t] = 0.f; }
    {
        float uA = fmaf(xA[i0], ns0, nb0);
        float uB = fmaf(xB[i0], ns0, nb0);
        float eA = __builtin_amdgcn_exp2f(fmaf(uA, SA0, SB0));
        float eB = __builtin_amdgcn_exp2f(fmaf(uB, SA0, SB0));
        float sA = __builtin_amdgcn_rcpf(1.0f + eA);
        float sB = __builtin_amdgcn_rcpf(1.0f + eB);
        s_lds[0][i0][lane][0] = SWe0 * sA;  s_lds[0][i0][lane][1] = SWv0 * sA;
        s_lds[1][i0][lane][0] = SWe0 * sB;  s_lds[1][i0][lane][1] = SWv0 * sB;
        if (has1) {
            float uA1 = fmaf(xA[i1], ns1, nb1);
            float uB1 = fmaf(xB[i1], ns1, nb1);
            float eA1 = __builtin_amdgcn_exp2f(fmaf(uA1, SA1, SB1));
            float eB1 = __builtin_amdgcn_exp2f(fmaf(uB1, SA1, SB1));
            float sA1 = __builtin_amdgcn_rcpf(1.0f + eA1);
            float sB1 = __builtin_amdgcn_rcpf(1.0f + eB1);
            s_lds[0][i1][lane][0] = SWe1 * sA1;  s_lds[0][i1][lane][1] = SWv1 * sA1;
            s_lds[1][i1][lane][0] = SWe1 * sB1;  s_lds[1][i1][lane][1] = SWv1 * sB1;
        }
    }
    lds_barrier();

    float vA = 0.f, vB = 0.f;

    for (int s = 0; s < S_; ++s) {
        // prefetch next step's inputs (wave-uniform addrs; consumed at k==1)
        const int s1 = (s + 1 < S_) ? (s + 1) : s;
        float xnA0 = xA[s1 * IN_ + i0];
        float xnB0 = xB[s1 * IN_ + i0];
        float xnA1 = has1 ? xA[s1 * IN_ + i1] : 0.f;
        float xnB1 = has1 ? xB[s1 * IN_ + i1] : 0.f;

        // fold sensory + leak into per-step bases (broadcast ds reads; consumed
        // only after unfold-0's butterfly -> latency overlapped)
        float aA = 0.f, dA = 0.f, aB = 0.f, dB = 0.f;
#pragma unroll
        for (int ci = 0; ci < IN_; ++ci) {
            float2 svA = *(const float2*)&s_lds[0][ci][myCol][0];
            float2 svB = *(const float2*)&s_lds[1][ci][myCol][0];
            aA += svA.x; dA += svA.y;
            aB += svB.x; dB += svB.y;
        }
        const float nbA = gv + aA, dbA = dbase + dA;
        const float nbB = gv + aB, dbB = dbase + dB;

#pragma unroll
        for (int k = 0; k < UNF; ++k) {
            const int p = k & 1;
            // issue all 8 broadcast v-reads up front: latencies overlap
            float4 a0 = *(const float4*)&vbuf[p][0][jb];
            float4 a1 = *(const float4*)&vbuf[p][0][jb + 4];
            float4 a2 = *(const float4*)&vbuf[p][0][jb + 8];
            float4 a3 = *(const float4*)&vbuf[p][0][jb + 12];
            float4 b0 = *(const float4*)&vbuf[p][1][jb];
            float4 b1 = *(const float4*)&vbuf[p][1][jb + 4];
            float4 b2 = *(const float4*)&vbuf[p][1][jb + 8];
            float4 b3 = *(const float4*)&vbuf[p][1][jb + 12];
            const float vjA[16] = {a0.x,a0.y,a0.z,a0.w, a1.x,a1.y,a1.z,a1.w,
                                   a2.x,a2.y,a2.z,a2.w, a3.x,a3.y,a3.z,a3.w};
            const float vjB[16] = {b0.x,b0.y,b0.z,b0.w, b1.x,b1.y,b1.z,b1.w,
                                   b2.x,b2.y,b2.z,b2.w, b3.x,b3.y,b3.z,b3.w};

            float pnA = 0.f, pdA = 0.f, pnB = 0.f, pdB = 0.f;
#pragma unroll
            for (int jj = 0; jj < 16; ++jj) {
                float eA  = __builtin_amdgcn_exp2f(fmaf(vjA[jj], A[jj], Bc[jj]));
                float eB  = __builtin_amdgcn_exp2f(fmaf(vjB[jj], A[jj], Bc[jj]));
                float sgA = __builtin_amdgcn_rcpf(1.0f + eA);
                float sgB = __builtin_amdgcn_rcpf(1.0f + eB);
                pnA = fmaf(We[jj], sgA, pnA);
                pdA = fmaf(Wr[jj], sgA, pdA);
                pnB = fmaf(We[jj], sgB, pnB);
                pdB = fmaf(Wr[jj], sgB, pdB);
            }
            // VALU butterflies over cc (lane bits 4,5): full column sums
            pnA = red16(pnA);  pdA = red16(pdA);
            pnB = red16(pnB);  pdB = red16(pdB);
            pnA = red32(pnA);  pdA = red32(pdA);
            pnB = red32(pnB);  pdB = red32(pdB);

            vA = fmaf(cmt, vA, nbA + pnA) * __builtin_amdgcn_rcpf(dbA + pdA);
            vB = fmaf(cmt, vB, nbB + pnB) * __builtin_amdgcn_rcpf(dbB + pdB);

            // publish v for next unfold (double-buffered, one writer per column)
            if (cc == 0) {
                vbuf[p ^ 1][0][myCol] = vA;
                vbuf[p ^ 1][1][myCol] = vB;
            }

            if (k == 1) {
                // sensory activations for step s+1 (step-s readers are before
                // the k=0 barrier; step-s+1 readers are 4 barriers later)
                float uA = fmaf(xnA0, ns0, nb0);
                float uB = fmaf(xnB0, ns0, nb0);
                float eA = __builtin_amdgcn_exp2f(fmaf(uA, SA0, SB0));
                float eB = __builtin_amdgcn_exp2f(fmaf(uB, SA0, SB0));
                float sA = __builtin_amdgcn_rcpf(1.0f + eA);
                float sB = __builtin_amdgcn_rcpf(1.0f + eB);
                s_lds[0][i0][lane][0] = SWe0 * sA;  s_lds[0][i0][lane][1] = SWv0 * sA;
                s_lds[1][i0][lane][0] = SWe0 * sB;  s_lds[1][i0][lane][1] = SWv0 * sB;
                if (has1) {
                    float uA1 = fmaf(xnA1, ns1, nb1);
                    float uB1 = fmaf(xnB1, ns1, nb1);
                    float eA1 = __builtin_amdgcn_exp2f(fmaf(uA1, SA1, SB1));
                    float eB1 = __builtin_amdgcn_exp2f(fmaf(uB1, SA1, SB1));
                    float sA1 = __builtin_amdgcn_rcpf(1.0f + eA1);
                    float sB1 = __builtin_amdgcn_rcpf(1.0f + eB1);
                    s_lds[0][i1][lane][0] = SWe1 * sA1;  s_lds[0][i1][lane][1] = SWv1 * sA1;
                    s_lds[1][i1][lane][0] = SWe1 * sB1;  s_lds[1][i1][lane][1] = SWv1 * sB1;
                }
            }
            lds_barrier();
        }

        // motor outputs: columns 0..2 live in lanes 0..2 of wave 0
        if (t < MOT_) {
            oA[s * MOT_ + t] = fmaf(vA, OW, OB);
            oB[s * MOT_ + t] = fmaf(vB, OW, OB);
        }
    }
}

extern "C" void kernel_launch(void* const* d_in, const int* in_sizes, int n_in,
                              void* d_out, int out_size, void* d_ws, size_t ws_size,
                              hipStream_t stream) {
    (void)in_sizes; (void)n_in; (void)d_ws; (void)ws_size; (void)out_size;
    const float* x       = (const float*)d_in[0];
    const float* mean_us = (const float*)d_in[1];
    const float* std_us  = (const float*)d_in[2];
    const float* input_w = (const float*)d_in[3];
    const float* input_b = (const float*)d_in[4];
    const float* out_w   = (const float*)d_in[5];
    const float* out_b   = (const float*)d_in[6];
    const float* gleak   = (const float*)d_in[7];
    const float* vleak   = (const float*)d_in[8];
    const float* cm      = (const float*)d_in[9];
    const float* sW      = (const float*)d_in[10];
    const float* sMu     = (const float*)d_in[11];
    const float* sSig    = (const float*)d_in[12];
    const float* sErev   = (const float*)d_in[13];
    const float* W       = (const float*)d_in[14];
    const float* Mu      = (const float*)d_in[15];
    const float* Sig     = (const float*)d_in[16];
    const float* Erev    = (const float*)d_in[17];
    float* out = (float*)d_out;

    ltc_kernel<<<dim3(B_ / 2), dim3(256), 0, stream>>>(
        x, mean_us, std_us, input_w, input_b, out_w, out_b,
        gleak, vleak, cm, sW, sMu, sSig, sErev, W, Mu, Sig, Erev, out);
}

// Round 7
// 10158.242 us; speedup vs baseline: 1.6351x; 1.6351x over previous
//
#include <hip/hip_runtime.h>

#define B_ 128
#define S_ 4096
#define IN_ 6
#define N_ 64
#define MOT_ 3
#define UNF 6
#define EPS_ 1e-8f
#define LOG2E 1.4426950408889634f

// ---- VALU-pipe cross-lane pair-sums over lane bits 4 and 5 ----
__device__ __forceinline__ float red16(float x) {
#if __has_builtin(__builtin_amdgcn_permlane16_swap)
    auto r = __builtin_amdgcn_permlane16_swap(__float_as_int(x), __float_as_int(x),
                                              false, false);
    return __int_as_float((int)r[0]) + __int_as_float((int)r[1]);
#else
    return x + __shfl_xor(x, 16, 64);
#endif
}
__device__ __forceinline__ float red32(float x) {
#if __has_builtin(__builtin_amdgcn_permlane32_swap)
    auto r = __builtin_amdgcn_permlane32_swap(__float_as_int(x), __float_as_int(x),
                                              false, false);
    return __int_as_float((int)r[0]) + __int_as_float((int)r[1]);
#else
    return x + __shfl_xor(x, 32, 64);
#endif
}

// barrier with LDS-only drain (no vmcnt: global loads/stores stay in flight)
__device__ __forceinline__ void lds_barrier() {
    asm volatile("s_waitcnt lgkmcnt(0)" ::: "memory");
    __builtin_amdgcn_s_barrier();
}

// One workgroup per batch chain. 256 threads = 4 waves = 1 wave/SIMD.
// Wave w owns output columns w*16..w*16+15; lane l = (cc=l>>4 j-chunk of 16,
// ii=l&15 col). Per unfold: 16 synapses/lane computed as FOUR quad-rational
// combines (1 rcp per 4 synapses, trans 32->20 instrs), then 2-stage VALU
// butterfly (permlane16/32_swap) -> full column sums in-register.
// ONE lgkm-only barrier per unfold; x prefetch forced to VMEM (vmcnt) so the
// barrier never drains an SMEM load.
__launch_bounds__(256, 1)
__global__ void ltc_kernel(
    const float* __restrict__ x,
    const float* __restrict__ mean_us, const float* __restrict__ std_us,
    const float* __restrict__ input_w, const float* __restrict__ input_b,
    const float* __restrict__ output_w, const float* __restrict__ output_b,
    const float* __restrict__ gleak, const float* __restrict__ vleak,
    const float* __restrict__ cm,
    const float* __restrict__ sW, const float* __restrict__ sMu,
    const float* __restrict__ sSig, const float* __restrict__ sErev,
    const float* __restrict__ W, const float* __restrict__ Mu,
    const float* __restrict__ Sig, const float* __restrict__ Erev,
    float* __restrict__ out)
{
    const int b    = blockIdx.x;
    const int t    = threadIdx.x;
    const int lane = t & 63;
    const int w    = t >> 6;      // wave 0..3
    const int cc   = lane >> 4;   // j-chunk 0..3 (16 j's each)
    const int ii   = lane & 15;   // column within wave's block
    const int myCol = w * 16 + ii;
    const int jb   = cc * 16;

    __shared__ __align__(16) float vbuf[2][N_];
    __shared__ float s_lds[IN_][N_][2];   // {wns_term, wds_term} per (input, col)

    // --- recurrent synapse params: 16 synapses (j=jb..jb+15) of column myCol ---
    // sigma((v-mu)*sig) = 1/t, t = 1+exp2(v*A + Bc), A=-sig*log2e, Bc=mu*sig*log2e
    float A[16], Bc[16], Wr[16], We[16];
#pragma unroll
    for (int jj = 0; jj < 16; ++jj) {
        int idx = (jb + jj) * N_ + myCol;
        float sg = Sig[idx], m = Mu[idx], ww = W[idx], e = Erev[idx];
        A[jj]  = -sg * LOG2E;
        Bc[jj] = m * sg * LOG2E;
        Wr[jj] = ww;
        We[jj] = ww * e;
    }

    // --- per-column state consts ---
    const float cmt = cm[myCol] * (float)UNF;
    const float glk = gleak[myCol];
    const float gv  = glk * vleak[myCol];
    const float dbase = cmt + glk + EPS_;

    // --- sensory params: wave w handles input w; waves 0,1 also input w+4 ---
    const int i0 = w;             // always valid (w<4 < IN_=6)
    const int i1 = w + 4;         // valid for w<2
    const bool has1 = (w < 2);
    float SA0, SB0, SWv0, SWe0, ns0, nb0;
    {
        int idx = i0 * N_ + lane;
        float sg = sSig[idx], m = sMu[idx], ww = sW[idx], e = sErev[idx];
        SA0 = -sg * LOG2E; SB0 = m * sg * LOG2E; SWv0 = ww; SWe0 = ww * e;
        ns0 = input_w[i0] / std_us[i0];
        nb0 = input_b[i0] - mean_us[i0] / std_us[i0] * input_w[i0];
    }
    float SA1 = 0.f, SB1 = 0.f, SWv1 = 0.f, SWe1 = 0.f, ns1 = 0.f, nb1 = 0.f;
    if (has1) {
        int idx = i1 * N_ + lane;
        float sg = sSig[idx], m = sMu[idx], ww = sW[idx], e = sErev[idx];
        SA1 = -sg * LOG2E; SB1 = m * sg * LOG2E; SWv1 = ww; SWe1 = ww * e;
        ns1 = input_w[i1] / std_us[i1];
        nb1 = input_b[i1] - mean_us[i1] / std_us[i1] * input_w[i1];
    }

    // --- output consts (lanes 0..2 of wave 0 hold motor columns 0..2) ---
    float OW = 0.f, OB = 0.f;
    if (t < MOT_) {
        OW = output_w[t] * std_us[t];
        OB = output_b[t] * std_us[t] + mean_us[t];
    }

    const float* xb = x + (size_t)b * S_ * IN_;
    float* ob = out + (size_t)b * S_ * MOT_;

    // --- init: v=0, sensory activations for step 0 ---
    if (t < N_) vbuf[0][t] = 0.f;
    {
        float u  = fmaf(xb[i0], ns0, nb0);
        float e  = __builtin_amdgcn_exp2f(fmaf(u, SA0, SB0));
        float sg = __builtin_amdgcn_rcpf(1.0f + e);
        s_lds[i0][lane][0] = SWe0 * sg;
        s_lds[i0][lane][1] = SWv0 * sg;
        if (has1) {
            float u1  = fmaf(xb[i1], ns1, nb1);
            float e1  = __builtin_amdgcn_exp2f(fmaf(u1, SA1, SB1));
            float sg1 = __builtin_amdgcn_rcpf(1.0f + e1);
            s_lds[i1][lane][0] = SWe1 * sg1;
            s_lds[i1][lane][1] = SWv1 * sg1;
        }
    }
    lds_barrier();

    float v_my = 0.f;

    for (int s = 0; s < S_; ++s) {
        // prefetch next step's input. Force offsets into VGPRs so the loads
        // are VMEM (vmcnt) global_loads, never SMEM (lgkm) s_loads: the
        // lds_barrier drains lgkmcnt only, so these stay in flight freely.
        const int s1 = (s + 1 < S_) ? (s + 1) : s;
        int off0 = s1 * IN_ + i0;
        asm volatile("" : "+v"(off0));
        float xn0 = xb[off0];
        float xn1 = 0.f;
        if (has1) {
            int off1 = s1 * IN_ + i1;
            asm volatile("" : "+v"(off1));
            xn1 = xb[off1];
        }

        // fold sensory + leak into per-step bases (broadcast ds reads; consumed
        // only after unfold-0's butterfly -> latency overlapped)
        float a = 0.f, d = 0.f;
#pragma unroll
        for (int ci = 0; ci < IN_; ++ci) {
            float2 sv = *(const float2*)&s_lds[ci][myCol][0];
            a += sv.x; d += sv.y;
        }
        const float nb = gv + a;
        const float db = dbase + d;

#pragma unroll
        for (int k = 0; k < UNF; ++k) {
            const int p = k & 1;
            // broadcast-read the 16 v's of this lane's j-chunk (4x ds_read_b128)
            float4 v0 = *(const float4*)&vbuf[p][jb];
            float4 v1 = *(const float4*)&vbuf[p][jb + 4];
            float4 v2 = *(const float4*)&vbuf[p][jb + 8];
            float4 v3 = *(const float4*)&vbuf[p][jb + 12];
            const float vj[16] = {v0.x, v0.y, v0.z, v0.w, v1.x, v1.y, v1.z, v1.w,
                                  v2.x, v2.y, v2.z, v2.w, v3.x, v3.y, v3.z, v3.w};

            // FOUR quad-rational combines: sum_{i in quad} w_i/t_i
            //   = [ (w0*t1+w1*t0)*P23 + (w2*t3+w3*t2)*P01 ] / (P01*P23)
            // one rcp per quad; We- and Wr-numerators share all t/P products.
            float pn = 0.f, pd = 0.f;
#pragma unroll
            for (int q = 0; q < 4; ++q) {
                const int j0 = q * 4;
                float t0 = 1.0f + __builtin_amdgcn_exp2f(fmaf(vj[j0+0], A[j0+0], Bc[j0+0]));
                float t1 = 1.0f + __builtin_amdgcn_exp2f(fmaf(vj[j0+1], A[j0+1], Bc[j0+1]));
                float t2 = 1.0f + __builtin_amdgcn_exp2f(fmaf(vj[j0+2], A[j0+2], Bc[j0+2]));
                float t3 = 1.0f + __builtin_amdgcn_exp2f(fmaf(vj[j0+3], A[j0+3], Bc[j0+3]));
                float p01 = t0 * t1, p23 = t2 * t3;
                float r   = __builtin_amdgcn_rcpf(p01 * p23);
                float ne01 = fmaf(We[j0+0], t1, We[j0+1] * t0);
                float ne23 = fmaf(We[j0+2], t3, We[j0+3] * t2);
                float nr01 = fmaf(Wr[j0+0], t1, Wr[j0+1] * t0);
                float nr23 = fmaf(Wr[j0+2], t3, Wr[j0+3] * t2);
                float NE = fmaf(ne01, p23, ne23 * p01);
                float NR = fmaf(nr01, p23, nr23 * p01);
                pn = fmaf(NE, r, pn);
                pd = fmaf(NR, r, pd);
            }

            // VALU butterfly over cc (lane bits 4,5): full column sums
            pn = red16(pn);  pd = red16(pd);
            pn = red32(pn);  pd = red32(pd);

            float num = fmaf(cmt, v_my, nb + pn);
            v_my = num * __builtin_amdgcn_rcpf(db + pd);

            // publish v for next unfold (double-buffered, one writer per column)
            if (cc == 0) vbuf[p ^ 1][myCol] = v_my;

            if (k == 1) {
                // sensory activations for step s+1 (step-s readers are before
                // the k=0 barrier; step-s+1 readers are 4 barriers later)
                float u  = fmaf(xn0, ns0, nb0);
                float e2 = __builtin_amdgcn_exp2f(fmaf(u, SA0, SB0));
                float sg = __builtin_amdgcn_rcpf(1.0f + e2);
                s_lds[i0][lane][0] = SWe0 * sg;
                s_lds[i0][lane][1] = SWv0 * sg;
                if (has1) {
                    float u1  = fmaf(xn1, ns1, nb1);
                    float e3  = __builtin_amdgcn_exp2f(fmaf(u1, SA1, SB1));
                    float sg1 = __builtin_amdgcn_rcpf(1.0f + e3);
                    s_lds[i1][lane][0] = SWe1 * sg1;
                    s_lds[i1][lane][1] = SWv1 * sg1;
                }
            }
            lds_barrier();
        }

        // motor outputs: columns 0..2 live in lanes 0..2 of wave 0
        if (t < MOT_) ob[s * MOT_ + t] = fmaf(v_my, OW, OB);
    }
}

extern "C" void kernel_launch(void* const* d_in, const int* in_sizes, int n_in,
                              void* d_out, int out_size, void* d_ws, size_t ws_size,
                              hipStream_t stream) {
    (void)in_sizes; (void)n_in; (void)d_ws; (void)ws_size; (void)out_size;
    const float* x       = (const float*)d_in[0];
    const float* mean_us = (const float*)d_in[1];
    const float* std_us  = (const float*)d_in[2];
    const float* input_w = (const float*)d_in[3];
    const float* input_b = (const float*)d_in[4];
    const float* out_w   = (const float*)d_in[5];
    const float* out_b   = (const float*)d_in[6];
    const float* gleak   = (const float*)d_in[7];
    const float* vleak   = (const float*)d_in[8];
    const float* cm      = (const float*)d_in[9];
    const float* sW      = (const float*)d_in[10];
    const float* sMu     = (const float*)d_in[11];
    const float* sSig    = (const float*)d_in[12];
    const float* sErev   = (const float*)d_in[13];
    const float* W       = (const float*)d_in[14];
    const float* Mu      = (const float*)d_in[15];
    const float* Sig     = (const float*)d_in[16];
    const float* Erev    = (const float*)d_in[17];
    float* out = (float*)d_out;

    ltc_kernel<<<dim3(B_), dim3(256), 0, stream>>>(
        x, mean_us, std_us, input_w, input_b, out_w, out_b,
        gleak, vleak, cm, sW, sMu, sSig, sErev, W, Mu, Sig, Erev, out);
}